// Round 3
// baseline (361.425 us; speedup 1.0000x reference)
//
#include <hip/hip_runtime.h>

#define Bsz 8
#define Ssz 128
#define Dsz 512
#define Lsz 512
#define Rsz 50
#define Mrows (Bsz * Ssz)          // 1024
#define SLOT (Mrows * Lsz)         // 524288 floats per ws slot
#define BSLOT (Lsz * Ssz)          // 65536: per-b stride of transposed slots
#define OUTMAT (Bsz * Ssz * Ssz)   // 131072

typedef __attribute__((ext_vector_type(8))) short bf16x8;
typedef __attribute__((ext_vector_type(4))) float f32x4;

struct K1Args {
  const float* W1[4];
  const float* b1[4];
};

__device__ __forceinline__ float fast_tanh(float x) {
  float e = __expf(2.0f * x);
  return 1.0f - 2.0f * __builtin_amdgcn_rcpf(e + 1.0f);
}

__device__ __forceinline__ short f2bf(float x) {
  // RNE fp32 -> bf16 bits
  union { float f; unsigned u; } v; v.f = x;
  unsigned r = v.u + 0x7FFFu + ((v.u >> 16) & 1u);
  return (short)(r >> 16);
}

// truncating hi/lo split: x ~= hi + lo with hi,lo bf16 (error ~2^-14 rel)
__device__ __forceinline__ void split_bf(float x, short& hi, short& lo) {
  unsigned u = __float_as_uint(x);
  hi = (short)(u >> 16);
  float hif = __uint_as_float(u & 0xFFFF0000u);
  float lof = x - hif;                 // exact
  lo = (short)(__float_as_uint(lof) >> 16);
}

// tanh(a+b) from ta=tanh(a), tb=tanh(b)
__device__ __forceinline__ float tpair(float ta, float tb) {
  return (ta + tb) * __builtin_amdgcn_rcpf(fmaf(ta, tb, 1.0f));
}

// ---------------------------------------------------------------------------
// Kernel 1: projections via bf16-split MFMA (3 products ~ fp32 accuracy).
// side = h*2+r. Epilogue: +b1 (left only), tanh, store fp32:
//   slots 0,2,4,6,7 row-major [m][l]; slots 1,3,5 transposed [b][l][j].
// wg 256 thr = 4 waves, tile 64m x 128n; wave tile 32m x 64n (2x4 MFMA tiles).
// ---------------------------------------------------------------------------
__global__ __launch_bounds__(256) void gemm_lr_mfma(const float* __restrict__ x,
                                                    K1Args a,
                                                    float* __restrict__ ws) {
  const int side = blockIdx.z;
  const int h = side >> 1, r = side & 1;
  const float* __restrict__ W = a.W1[h] + r * (Dsz * Lsz);
  const float* __restrict__ bias = a.b1[h];
  const int tid = threadIdx.x;
  const int w = tid >> 6, lane = tid & 63;
  const int lm = lane & 15, q = lane >> 4;
  const int mw = blockIdx.y * 64 + (w & 1) * 32;
  const int nw = blockIdx.x * 128 + (w >> 1) * 64;

  f32x4 acc[2][4];
#pragma unroll
  for (int mt = 0; mt < 2; ++mt)
#pragma unroll
    for (int nt = 0; nt < 4; ++nt) {
      acc[mt][nt].x = 0.f; acc[mt][nt].y = 0.f;
      acc[mt][nt].z = 0.f; acc[mt][nt].w = 0.f;
    }

  for (int kc = 0; kc < Dsz; kc += 32) {
    const int k0 = kc + q * 8;
    bf16x8 ahi[2], alo[2];
#pragma unroll
    for (int mt = 0; mt < 2; ++mt) {
      const float* xp = x + (mw + mt * 16 + lm) * Dsz + k0;
      float4 v0 = *(const float4*)xp;
      float4 v1 = *(const float4*)(xp + 4);
      const float* vf0 = (const float*)&v0;
      const float* vf1 = (const float*)&v1;
#pragma unroll
      for (int e = 0; e < 4; ++e) {
        short hi, lo;
        split_bf(vf0[e], hi, lo); ahi[mt][e] = hi; alo[mt][e] = lo;
        split_bf(vf1[e], hi, lo); ahi[mt][e + 4] = hi; alo[mt][e + 4] = lo;
      }
    }
    bf16x8 bhi[4], blo[4];
#pragma unroll
    for (int nt = 0; nt < 4; ++nt) {
      const float* wp = W + k0 * Lsz + (nw + nt * 16 + lm);
      float vv[8];
#pragma unroll
      for (int jj = 0; jj < 8; ++jj) vv[jj] = wp[jj * Lsz];
#pragma unroll
      for (int jj = 0; jj < 8; ++jj) {
        short hi, lo;
        split_bf(vv[jj], hi, lo); bhi[nt][jj] = hi; blo[nt][jj] = lo;
      }
    }
#pragma unroll
    for (int mt = 0; mt < 2; ++mt)
#pragma unroll
      for (int nt = 0; nt < 4; ++nt) {
        acc[mt][nt] = __builtin_amdgcn_mfma_f32_16x16x32_bf16(
            ahi[mt], bhi[nt], acc[mt][nt], 0, 0, 0);
        acc[mt][nt] = __builtin_amdgcn_mfma_f32_16x16x32_bf16(
            ahi[mt], blo[nt], acc[mt][nt], 0, 0, 0);
        acc[mt][nt] = __builtin_amdgcn_mfma_f32_16x16x32_bf16(
            alo[mt], bhi[nt], acc[mt][nt], 0, 0, 0);
      }
  }

  float* slot = ws + side * SLOT;
  const bool transposed = (r == 1) && (h < 3);  // sides 1,3,5
#pragma unroll
  for (int nt = 0; nt < 4; ++nt) {
    const int n_out = nw + nt * 16 + lm;
    const float bb = (r == 0) ? bias[n_out] : 0.0f;
#pragma unroll
    for (int mt = 0; mt < 2; ++mt) {
#pragma unroll
      for (int reg = 0; reg < 4; ++reg) {
        const int m_out = mw + mt * 16 + q * 4 + reg;
        float v;
        if (reg == 0) v = acc[mt][nt].x;
        else if (reg == 1) v = acc[mt][nt].y;
        else if (reg == 2) v = acc[mt][nt].z;
        else v = acc[mt][nt].w;
        const float t = fast_tanh(v + bb);
        if (transposed) {
          const int bb_ = m_out >> 7, j = m_out & 127;
          slot[bb_ * BSLOT + n_out * Ssz + j] = t;
        } else {
          slot[m_out * Lsz + n_out] = t;
        }
      }
    }
  }
}

// ---------------------------------------------------------------------------
// Kernel 2: scalar heads via tanh-identity. No LDS. 512 thr = 128 j x 4 i.
// tb reads lane-coalesced from transposed slots; ta/w2 wave-uniform.
// ---------------------------------------------------------------------------
__global__ __launch_bounds__(512) void pair_scalar2(
    const float* __restrict__ ws,
    const float* __restrict__ w2a, const float* __restrict__ w2b,
    const float* __restrict__ w2c,
    const float* __restrict__ b2a, const float* __restrict__ b2b,
    const float* __restrict__ b2c,
    float* __restrict__ out) {
  const int b = blockIdx.y;
  const int tid = threadIdx.x;
  const int j = tid & 127;
  const int ih = tid >> 7;             // 0..3
  const int i = blockIdx.x * 4 + ih;
  const int jmin = (tid >> 6) & 1 ? 64 : 0;  // wave's min j
  const bool do_span = (i >= jmin);

  const float* ta0 = ws + 0 * SLOT + (b * Ssz + i) * Lsz;
  const float* ta1 = ws + 2 * SLOT + (b * Ssz + i) * Lsz;
  const float* ta2 = ws + 4 * SLOT + (b * Ssz + i) * Lsz;
  const float* tb0 = ws + 1 * SLOT + b * BSLOT + j;
  const float* tb1 = ws + 3 * SLOT + b * BSLOT + j;
  const float* tb2 = ws + 5 * SLOT + b * BSLOT + j;

  float acc0 = 0.f, acc1 = 0.f, acc2 = 0.f;
#pragma unroll 4
  for (int l = 0; l < Lsz; ++l) {
    const float b1v = tb1[l * Ssz];
    const float a1v = ta1[l];
    acc1 = fmaf(tpair(a1v, b1v), w2b[l], acc1);
    const float b2v = tb2[l * Ssz];
    const float a2v = ta2[l];
    acc2 = fmaf(tpair(a2v, b2v), w2c[l], acc2);
    if (do_span) {
      const float b0v = tb0[l * Ssz];
      const float a0v = ta0[l];
      acc0 = fmaf(tpair(a0v, b0v), w2a[l], acc0);
    }
  }

  const int base = (b * Ssz + i) * Ssz + j;
  out[OUTMAT + base] = acc1 + b2b[0];
  out[2 * OUTMAT + base] = acc2 + b2c[0];
  if (do_span && j <= i) {
    const float v = acc0 + b2a[0];
    out[(b * Ssz + i) * Ssz + j] = v;
    out[(b * Ssz + j) * Ssz + i] = v;
  }
}

// ---------------------------------------------------------------------------
// Kernel 2.5: transpose + bf16-convert label W2 [512l][50o] -> [64o][512l].
// Output overwrites first 64KB of ws slot 0 (safe: pair_scalar2 is done).
// ---------------------------------------------------------------------------
__global__ __launch_bounds__(256) void w2prep(const float* __restrict__ W2,
                                              unsigned short* __restrict__ o) {
  int idx = blockIdx.x * 256 + threadIdx.x;  // 64*512 total
  int oo = idx >> 9, k = idx & 511;
  float v = (oo < Rsz) ? W2[k * Rsz + oo] : 0.0f;
  o[oo * Lsz + k] = (unsigned short)f2bf(v);
}

// ---------------------------------------------------------------------------
// Kernel 3: label head via bf16 MFMA + tanh-identity. wg = 2 i's (4 waves);
// wave covers one i, 64 j's (4 m-tiles) x 64 o (4 n-tiles), K=512.
// ---------------------------------------------------------------------------
__global__ __launch_bounds__(256) void pair_label2(
    const float* __restrict__ ws, const unsigned short* __restrict__ W2bfT,
    const float* __restrict__ b2, float* __restrict__ out) {
  const int b = blockIdx.y;
  const int tid = threadIdx.x;
  const int w = tid >> 6, lane = tid & 63;
  const int lm = lane & 15, q = lane >> 4;
  const int i = blockIdx.x * 2 + (w >> 1);
  const int jb = (w & 1) * 64;

  const float* Lrow = ws + 6 * SLOT + (b * Ssz + i) * Lsz;
  const float* Rbase = ws + 7 * SLOT + (long)b * Ssz * Lsz;
  float* out3 = out + 3 * OUTMAT;

  f32x4 acc[4][4];
#pragma unroll
  for (int mt = 0; mt < 4; ++mt)
#pragma unroll
    for (int nt = 0; nt < 4; ++nt) {
      acc[mt][nt].x = 0.f; acc[mt][nt].y = 0.f;
      acc[mt][nt].z = 0.f; acc[mt][nt].w = 0.f;
    }

  for (int kc = 0; kc < Lsz; kc += 32) {
    const int k0 = kc + q * 8;
    float4 lf0 = *(const float4*)(Lrow + k0);
    float4 lf1 = *(const float4*)(Lrow + k0 + 4);
    const float* l0 = (const float*)&lf0;
    const float* l1 = (const float*)&lf1;
    bf16x8 af[4];
#pragma unroll
    for (int mt = 0; mt < 4; ++mt) {
      const float* rp = Rbase + (jb + mt * 16 + lm) * Lsz + k0;
      float4 r0 = *(const float4*)rp;
      float4 r1 = *(const float4*)(rp + 4);
      const float* rf0 = (const float*)&r0;
      const float* rf1 = (const float*)&r1;
      bf16x8 aa;
#pragma unroll
      for (int e = 0; e < 4; ++e) {
        aa[e] = f2bf(tpair(l0[e], rf0[e]));
        aa[e + 4] = f2bf(tpair(l1[e], rf1[e]));
      }
      af[mt] = aa;
    }
    bf16x8 bfr[4];
#pragma unroll
    for (int nt = 0; nt < 4; ++nt)
      bfr[nt] = *(const bf16x8*)(W2bfT + (nt * 16 + lm) * Lsz + k0);
#pragma unroll
    for (int mt = 0; mt < 4; ++mt)
#pragma unroll
      for (int nt = 0; nt < 4; ++nt)
        acc[mt][nt] = __builtin_amdgcn_mfma_f32_16x16x32_bf16(
            af[mt], bfr[nt], acc[mt][nt], 0, 0, 0);
  }

#pragma unroll
  for (int nt = 0; nt < 4; ++nt) {
    const int o = nt * 16 + lm;
    if (o >= Rsz) continue;
    const float bias = b2[o];
#pragma unroll
    for (int mt = 0; mt < 4; ++mt) {
#pragma unroll
      for (int reg = 0; reg < 4; ++reg) {
        const int j = jb + mt * 16 + q * 4 + reg;
        const long base = ((long)(b * Ssz + i) * Ssz + j) * Rsz;
        float v;
        if (reg == 0) v = acc[mt][nt].x;
        else if (reg == 1) v = acc[mt][nt].y;
        else if (reg == 2) v = acc[mt][nt].z;
        else v = acc[mt][nt].w;
        out3[base + o] = v + bias;
      }
    }
  }
}

extern "C" void kernel_launch(void* const* d_in, const int* in_sizes, int n_in,
                              void* d_out, int out_size, void* d_ws,
                              size_t ws_size, hipStream_t stream) {
  (void)in_sizes; (void)n_in; (void)out_size; (void)ws_size;
  const float* x = (const float*)d_in[0];
  K1Args a;
  a.W1[0] = (const float*)d_in[1];  a.b1[0] = (const float*)d_in[2];
  a.W1[1] = (const float*)d_in[5];  a.b1[1] = (const float*)d_in[6];
  a.W1[2] = (const float*)d_in[9];  a.b1[2] = (const float*)d_in[10];
  a.W1[3] = (const float*)d_in[13]; a.b1[3] = (const float*)d_in[14];
  const float* w2a = (const float*)d_in[3];
  const float* b2a = (const float*)d_in[4];
  const float* w2b = (const float*)d_in[7];
  const float* b2b = (const float*)d_in[8];
  const float* w2c = (const float*)d_in[11];
  const float* b2c = (const float*)d_in[12];
  const float* W2l = (const float*)d_in[15];
  const float* b2l = (const float*)d_in[16];
  float* ws = (float*)d_ws;   // 8 slots x 2MB = 16MB (tanh'd projections)
  float* out = (float*)d_out;

  dim3 g1(Lsz / 128, Mrows / 64, 8);   // (4,16,8)
  gemm_lr_mfma<<<g1, 256, 0, stream>>>(x, a, ws);
  dim3 g2(Ssz / 4, Bsz);               // (32,8)
  pair_scalar2<<<g2, 512, 0, stream>>>(ws, w2a, w2b, w2c, b2a, b2b, b2c, out);
  unsigned short* W2bfT = (unsigned short*)ws;  // reuses slot 0 (done)
  w2prep<<<(64 * Lsz) / 256, 256, 0, stream>>>(W2l, W2bfT);
  dim3 g3(Ssz / 2, Bsz);               // (64,8)
  pair_label2<<<g3, 256, 0, stream>>>(ws, W2bfT, b2l, out);
}

// Round 4
// 223.075 us; speedup vs baseline: 1.6202x; 1.6202x over previous
//
#include <hip/hip_runtime.h>

#define Bsz 8
#define Ssz 128
#define Dsz 512
#define Lsz 512
#define Rsz 50
#define Mrows (Bsz * Ssz)          // 1024
#define SLOT (Mrows * Lsz)         // 524288 floats per ws slot
#define BSLOT (Lsz * Ssz)          // 65536: per-b stride of transposed slots
#define OUTMAT (Bsz * Ssz * Ssz)   // 131072

typedef __attribute__((ext_vector_type(8))) short bf16x8;
typedef __attribute__((ext_vector_type(4))) float f32x4;

struct K1Args {
  const float* W1[4];
  const float* b1[4];
};

__device__ __forceinline__ float fast_tanh(float x) {
  float e = __expf(2.0f * x);
  return 1.0f - 2.0f * __builtin_amdgcn_rcpf(e + 1.0f);
}

__device__ __forceinline__ short f2bf(float x) {
  // RNE fp32 -> bf16 bits
  union { float f; unsigned u; } v; v.f = x;
  unsigned r = v.u + 0x7FFFu + ((v.u >> 16) & 1u);
  return (short)(r >> 16);
}

// truncating hi/lo split: x ~= hi + lo with hi,lo bf16 (error ~2^-14 rel)
__device__ __forceinline__ void split_bf(float x, short& hi, short& lo) {
  unsigned u = __float_as_uint(x);
  hi = (short)(u >> 16);
  float hif = __uint_as_float(u & 0xFFFF0000u);
  float lof = x - hif;                 // exact
  lo = (short)(__float_as_uint(lof) >> 16);
}

// tanh(a+b) from ta=tanh(a), tb=tanh(b)
__device__ __forceinline__ float tpair(float ta, float tb) {
  return (ta + tb) * __builtin_amdgcn_rcpf(fmaf(ta, tb, 1.0f));
}

// ---------------------------------------------------------------------------
// Kernel 1: projections via bf16-split MFMA (3 products ~ fp32 accuracy).
// side = h*2+r. Epilogue: +b1 (left only), tanh, store fp32.
//   Scalar-head slots (h<3, both sides) stored TRANSPOSED [b][l][idx] so
//   pair_scalar3 can stage LDS tiles with coalesced row reads.
//   Label slots 6,7 stay row-major [m][l] for pair_label2.
// ---------------------------------------------------------------------------
__global__ __launch_bounds__(256) void gemm_lr_mfma(const float* __restrict__ x,
                                                    K1Args a,
                                                    float* __restrict__ ws) {
  const int side = blockIdx.z;
  const int h = side >> 1, r = side & 1;
  const float* __restrict__ W = a.W1[h] + r * (Dsz * Lsz);
  const float* __restrict__ bias = a.b1[h];
  const int tid = threadIdx.x;
  const int w = tid >> 6, lane = tid & 63;
  const int lm = lane & 15, q = lane >> 4;
  const int mw = blockIdx.y * 64 + (w & 1) * 32;
  const int nw = blockIdx.x * 128 + (w >> 1) * 64;

  f32x4 acc[2][4];
#pragma unroll
  for (int mt = 0; mt < 2; ++mt)
#pragma unroll
    for (int nt = 0; nt < 4; ++nt) {
      acc[mt][nt].x = 0.f; acc[mt][nt].y = 0.f;
      acc[mt][nt].z = 0.f; acc[mt][nt].w = 0.f;
    }

  for (int kc = 0; kc < Dsz; kc += 32) {
    const int k0 = kc + q * 8;
    bf16x8 ahi[2], alo[2];
#pragma unroll
    for (int mt = 0; mt < 2; ++mt) {
      const float* xp = x + (mw + mt * 16 + lm) * Dsz + k0;
      float4 v0 = *(const float4*)xp;
      float4 v1 = *(const float4*)(xp + 4);
      const float* vf0 = (const float*)&v0;
      const float* vf1 = (const float*)&v1;
#pragma unroll
      for (int e = 0; e < 4; ++e) {
        short hi, lo;
        split_bf(vf0[e], hi, lo); ahi[mt][e] = hi; alo[mt][e] = lo;
        split_bf(vf1[e], hi, lo); ahi[mt][e + 4] = hi; alo[mt][e + 4] = lo;
      }
    }
    bf16x8 bhi[4], blo[4];
#pragma unroll
    for (int nt = 0; nt < 4; ++nt) {
      const float* wp = W + k0 * Lsz + (nw + nt * 16 + lm);
      float vv[8];
#pragma unroll
      for (int jj = 0; jj < 8; ++jj) vv[jj] = wp[jj * Lsz];
#pragma unroll
      for (int jj = 0; jj < 8; ++jj) {
        short hi, lo;
        split_bf(vv[jj], hi, lo); bhi[nt][jj] = hi; blo[nt][jj] = lo;
      }
    }
#pragma unroll
    for (int mt = 0; mt < 2; ++mt)
#pragma unroll
      for (int nt = 0; nt < 4; ++nt) {
        acc[mt][nt] = __builtin_amdgcn_mfma_f32_16x16x32_bf16(
            ahi[mt], bhi[nt], acc[mt][nt], 0, 0, 0);
        acc[mt][nt] = __builtin_amdgcn_mfma_f32_16x16x32_bf16(
            ahi[mt], blo[nt], acc[mt][nt], 0, 0, 0);
        acc[mt][nt] = __builtin_amdgcn_mfma_f32_16x16x32_bf16(
            alo[mt], bhi[nt], acc[mt][nt], 0, 0, 0);
      }
  }

  float* slot = ws + side * SLOT;
  const bool transposed = (h < 3);   // all scalar-head sides
#pragma unroll
  for (int nt = 0; nt < 4; ++nt) {
    const int n_out = nw + nt * 16 + lm;
    const float bb = (r == 0) ? bias[n_out] : 0.0f;
#pragma unroll
    for (int mt = 0; mt < 2; ++mt) {
#pragma unroll
      for (int reg = 0; reg < 4; ++reg) {
        const int m_out = mw + mt * 16 + q * 4 + reg;
        float v;
        if (reg == 0) v = acc[mt][nt].x;
        else if (reg == 1) v = acc[mt][nt].y;
        else if (reg == 2) v = acc[mt][nt].z;
        else v = acc[mt][nt].w;
        const float t = fast_tanh(v + bb);
        if (transposed) {
          const int bb_ = m_out >> 7, idx = m_out & 127;
          slot[bb_ * BSLOT + n_out * Ssz + idx] = t;
        } else {
          slot[m_out * Lsz + n_out] = t;
        }
      }
    }
  }
}

// ---------------------------------------------------------------------------
// Kernel 2: scalar heads via tanh-identity + LDS tiling.
// grid (16 tiles, 8 b, 3 heads); block 256 thr; tile 32i x 32j; thread 2x2.
// L-chunks of 64 staged coalesced from transposed slots; span head skips
// strictly-upper tiles and mirror-writes the lower triangle.
// ---------------------------------------------------------------------------
__global__ __launch_bounds__(256) void pair_scalar3(
    const float* __restrict__ ws,
    const float* __restrict__ w2a, const float* __restrict__ w2b,
    const float* __restrict__ w2c,
    const float* __restrict__ b2a, const float* __restrict__ b2b,
    const float* __restrict__ b2c,
    float* __restrict__ out) {
  const int h = blockIdx.z;
  const int b = blockIdx.y;
  const int it = blockIdx.x >> 2, jt = blockIdx.x & 3;
  if (h == 0 && jt > it) return;   // span: strictly-upper tile
  const int i0 = it * 32, j0 = jt * 32;
  const int t = threadIdx.x;
  const int tj = t & 15, ti = t >> 4;

  const float* __restrict__ A  = ws + (2 * h) * SLOT + b * BSLOT;      // [l][i]
  const float* __restrict__ Bt = ws + (2 * h + 1) * SLOT + b * BSLOT;  // [l][j]
  const float* __restrict__ w2 = (h == 0) ? w2a : (h == 1 ? w2b : w2c);
  const float bias = (h == 0) ? b2a[0] : (h == 1 ? b2b[0] : b2c[0]);

  __shared__ float Ls[64][36];
  __shared__ float Rs[64][36];
  __shared__ float w2s[64];

  float acc00 = 0.f, acc01 = 0.f, acc10 = 0.f, acc11 = 0.f;

  const int sl = t >> 3;        // 0..31
  const int sf = (t & 7) * 4;   // 0,4,...,28

  for (int lc = 0; lc < Lsz; lc += 64) {
    __syncthreads();
    *(float4*)&Ls[sl][sf]      = *(const float4*)(A  + (lc + sl) * Ssz + i0 + sf);
    *(float4*)&Ls[sl + 32][sf] = *(const float4*)(A  + (lc + sl + 32) * Ssz + i0 + sf);
    *(float4*)&Rs[sl][sf]      = *(const float4*)(Bt + (lc + sl) * Ssz + j0 + sf);
    *(float4*)&Rs[sl + 32][sf] = *(const float4*)(Bt + (lc + sl + 32) * Ssz + j0 + sf);
    if (t < 64) w2s[t] = w2[lc + t];
    __syncthreads();
#pragma unroll 4
    for (int l = 0; l < 64; ++l) {
      const float2 ta = *(const float2*)&Ls[l][ti * 2];
      const float2 tb = *(const float2*)&Rs[l][tj * 2];
      const float wv = w2s[l];
      acc00 = fmaf(tpair(ta.x, tb.x), wv, acc00);
      acc01 = fmaf(tpair(ta.x, tb.y), wv, acc01);
      acc10 = fmaf(tpair(ta.y, tb.x), wv, acc10);
      acc11 = fmaf(tpair(ta.y, tb.y), wv, acc11);
    }
  }

  const int i = i0 + ti * 2, j = j0 + tj * 2;
  const float av[2][2] = {{acc00, acc01}, {acc10, acc11}};
  if (h == 0) {
#pragma unroll
    for (int di = 0; di < 2; ++di)
#pragma unroll
      for (int dj = 0; dj < 2; ++dj) {
        const int ii = i + di, jj = j + dj;
        if (jj <= ii) {
          const float v = av[di][dj] + bias;
          out[(b * Ssz + ii) * Ssz + jj] = v;
          out[(b * Ssz + jj) * Ssz + ii] = v;
        }
      }
  } else {
    float* o = out + h * OUTMAT;
    o[(b * Ssz + i) * Ssz + j]           = av[0][0] + bias;
    o[(b * Ssz + i) * Ssz + j + 1]       = av[0][1] + bias;
    o[(b * Ssz + i + 1) * Ssz + j]       = av[1][0] + bias;
    o[(b * Ssz + i + 1) * Ssz + j + 1]   = av[1][1] + bias;
  }
}

// ---------------------------------------------------------------------------
// Kernel 2.5: transpose + bf16-convert label W2 [512l][50o] -> [64o][512l].
// Output overwrites first 64KB of ws slot 0 (safe: pair_scalar3 is done).
// ---------------------------------------------------------------------------
__global__ __launch_bounds__(256) void w2prep(const float* __restrict__ W2,
                                              unsigned short* __restrict__ o) {
  int idx = blockIdx.x * 256 + threadIdx.x;  // 64*512 total
  int oo = idx >> 9, k = idx & 511;
  float v = (oo < Rsz) ? W2[k * Rsz + oo] : 0.0f;
  o[oo * Lsz + k] = (unsigned short)f2bf(v);
}

// ---------------------------------------------------------------------------
// Kernel 3: label head via bf16 MFMA + tanh-identity. wg = 2 i's (4 waves);
// wave covers one i, 64 j's (4 m-tiles) x 64 o (4 n-tiles), K=512.
// ---------------------------------------------------------------------------
__global__ __launch_bounds__(256) void pair_label2(
    const float* __restrict__ ws, const unsigned short* __restrict__ W2bfT,
    const float* __restrict__ b2, float* __restrict__ out) {
  const int b = blockIdx.y;
  const int tid = threadIdx.x;
  const int w = tid >> 6, lane = tid & 63;
  const int lm = lane & 15, q = lane >> 4;
  const int i = blockIdx.x * 2 + (w >> 1);
  const int jb = (w & 1) * 64;

  const float* Lrow = ws + 6 * SLOT + (b * Ssz + i) * Lsz;
  const float* Rbase = ws + 7 * SLOT + (long)b * Ssz * Lsz;
  float* out3 = out + 3 * OUTMAT;

  f32x4 acc[4][4];
#pragma unroll
  for (int mt = 0; mt < 4; ++mt)
#pragma unroll
    for (int nt = 0; nt < 4; ++nt) {
      acc[mt][nt].x = 0.f; acc[mt][nt].y = 0.f;
      acc[mt][nt].z = 0.f; acc[mt][nt].w = 0.f;
    }

  for (int kc = 0; kc < Lsz; kc += 32) {
    const int k0 = kc + q * 8;
    float4 lf0 = *(const float4*)(Lrow + k0);
    float4 lf1 = *(const float4*)(Lrow + k0 + 4);
    const float* l0 = (const float*)&lf0;
    const float* l1 = (const float*)&lf1;
    bf16x8 af[4];
#pragma unroll
    for (int mt = 0; mt < 4; ++mt) {
      const float* rp = Rbase + (jb + mt * 16 + lm) * Lsz + k0;
      float4 r0 = *(const float4*)rp;
      float4 r1 = *(const float4*)(rp + 4);
      const float* rf0 = (const float*)&r0;
      const float* rf1 = (const float*)&r1;
      bf16x8 aa;
#pragma unroll
      for (int e = 0; e < 4; ++e) {
        aa[e] = f2bf(tpair(l0[e], rf0[e]));
        aa[e + 4] = f2bf(tpair(l1[e], rf1[e]));
      }
      af[mt] = aa;
    }
    bf16x8 bfr[4];
#pragma unroll
    for (int nt = 0; nt < 4; ++nt)
      bfr[nt] = *(const bf16x8*)(W2bfT + (nt * 16 + lm) * Lsz + k0);
#pragma unroll
    for (int mt = 0; mt < 4; ++mt)
#pragma unroll
      for (int nt = 0; nt < 4; ++nt)
        acc[mt][nt] = __builtin_amdgcn_mfma_f32_16x16x32_bf16(
            af[mt], bfr[nt], acc[mt][nt], 0, 0, 0);
  }

#pragma unroll
  for (int nt = 0; nt < 4; ++nt) {
    const int o = nt * 16 + lm;
    if (o >= Rsz) continue;
    const float bias = b2[o];
#pragma unroll
    for (int mt = 0; mt < 4; ++mt) {
#pragma unroll
      for (int reg = 0; reg < 4; ++reg) {
        const int j = jb + mt * 16 + q * 4 + reg;
        const long base = ((long)(b * Ssz + i) * Ssz + j) * Rsz;
        float v;
        if (reg == 0) v = acc[mt][nt].x;
        else if (reg == 1) v = acc[mt][nt].y;
        else if (reg == 2) v = acc[mt][nt].z;
        else v = acc[mt][nt].w;
        out3[base + o] = v + bias;
      }
    }
  }
}

extern "C" void kernel_launch(void* const* d_in, const int* in_sizes, int n_in,
                              void* d_out, int out_size, void* d_ws,
                              size_t ws_size, hipStream_t stream) {
  (void)in_sizes; (void)n_in; (void)out_size; (void)ws_size;
  const float* x = (const float*)d_in[0];
  K1Args a;
  a.W1[0] = (const float*)d_in[1];  a.b1[0] = (const float*)d_in[2];
  a.W1[1] = (const float*)d_in[5];  a.b1[1] = (const float*)d_in[6];
  a.W1[2] = (const float*)d_in[9];  a.b1[2] = (const float*)d_in[10];
  a.W1[3] = (const float*)d_in[13]; a.b1[3] = (const float*)d_in[14];
  const float* w2a = (const float*)d_in[3];
  const float* b2a = (const float*)d_in[4];
  const float* w2b = (const float*)d_in[7];
  const float* b2b = (const float*)d_in[8];
  const float* w2c = (const float*)d_in[11];
  const float* b2c = (const float*)d_in[12];
  const float* W2l = (const float*)d_in[15];
  const float* b2l = (const float*)d_in[16];
  float* ws = (float*)d_ws;   // 8 slots x 2MB = 16MB (tanh'd projections)
  float* out = (float*)d_out;

  dim3 g1(Lsz / 128, Mrows / 64, 8);   // (4,16,8)
  gemm_lr_mfma<<<g1, 256, 0, stream>>>(x, a, ws);
  dim3 g2(16, Bsz, 3);                 // (tiles, b, head)
  pair_scalar3<<<g2, 256, 0, stream>>>(ws, w2a, w2b, w2c, b2a, b2b, b2c, out);
  unsigned short* W2bfT = (unsigned short*)ws;  // reuses slot 0 (done)
  w2prep<<<(64 * Lsz) / 256, 256, 0, stream>>>(W2l, W2bfT);
  dim3 g3(Ssz / 2, Bsz);               // (64,8)
  pair_label2<<<g3, 256, 0, stream>>>(ws, W2bfT, b2l, out);
}